// Round 9
// baseline (4162.632 us; speedup 1.0000x reference)
//
#include <hip/hip_runtime.h>
#include <math.h>

#define BB 32
#define EE 512
#define VV 8192
#define TT 16
#define LL 4
#define FFD 2048
#define NHD 8
#define HDD 64
#define LDP 520   // padded LDS pitch (bf16 elems)
#define RWP 516   // padded LDS pitch (f32 elems)
#define OLP 72    // small-tile LDS pitch (bf16): 144B rows, 16B-aligned
#define SCALE_EMB 22.627416997969522f

typedef __attribute__((ext_vector_type(8))) short bf16x8;
typedef __attribute__((ext_vector_type(4))) float f32x4;
typedef unsigned long long ull;

__device__ __forceinline__ f32x4 mfma16(bf16x8 a, bf16x8 b, f32x4 c){
  return __builtin_amdgcn_mfma_f32_16x16x32_bf16(a, b, c, 0, 0, 0);
}

// ---------------- helpers ----------------
__device__ __forceinline__ float wave_sum(float v){
  for (int o = 32; o; o >>= 1) v += __shfl_down(v, o);
  return __shfl(v, 0);
}
__device__ __forceinline__ unsigned short f_to_bf(float f){
  unsigned u = __float_as_uint(f);
  unsigned r = (u + 0x7fffu + ((u >> 16) & 1u)) >> 16;
  return (unsigned short)r;
}
__device__ __forceinline__ float2 bf2_to_f2(const unsigned short* p){
  unsigned u = *(const unsigned*)p;
  float2 r;
  r.x = __uint_as_float(u << 16);
  r.y = __uint_as_float(u & 0xffff0000u);
  return r;
}
union UF { ull u; unsigned short s[4]; };
__device__ __forceinline__ ull pkbf4(float a, float b, float c, float d){
  UF x; x.s[0] = f_to_bf(a); x.s[1] = f_to_bf(b); x.s[2] = f_to_bf(c); x.s[3] = f_to_bf(d); return x.u;
}

// fp32 VALU GEMM core (one-off prologue kernels k_penc/k_pca)
__device__ __forceinline__ void gemm_chunk(const float* __restrict__ wrow0, int ldw,
    const unsigned short* xs, float* wt, float acc[4][2]){
  const int t = threadIdx.x, fg = t & 15, bg = t >> 4;
  #pragma unroll 1
  for (int c = 0; c < 8; ++c){
    const int k0 = c*64;
    __syncthreads();
    {
      int i = t*4;
      #pragma unroll
      for (int p = 0; p < 4; ++p, i += 1024){
        const int fr = i >> 6, kk = i & 63;
        float4 v = *(const float4*)(wrow0 + (size_t)fr*ldw + k0 + kk);
        wt[(kk+0)*68 + fr] = v.x;
        wt[(kk+1)*68 + fr] = v.y;
        wt[(kk+2)*68 + fr] = v.z;
        wt[(kk+3)*68 + fr] = v.w;
      }
    }
    __syncthreads();
    const unsigned short* xr0 = xs + (bg*2)*EE + k0;
    const unsigned short* xr1 = xr0 + EE;
    #pragma unroll 8
    for (int k = 0; k < 64; k += 2){
      float w0[4], w1[4];
      *(float4*)w0 = *(const float4*)(wt + (k+0)*68 + fg*4);
      *(float4*)w1 = *(const float4*)(wt + (k+1)*68 + fg*4);
      float2 xv0 = bf2_to_f2(xr0 + k);
      float2 xv1 = bf2_to_f2(xr1 + k);
      #pragma unroll
      for (int i = 0; i < 4; ++i){
        acc[i][0] += w0[i]*xv0.x + w1[i]*xv0.y;
        acc[i][1] += w0[i]*xv1.x + w1[i]*xv1.y;
      }
    }
  }
}

// Stage [B,E] into padded-LDS bf16 with 512 threads; optional pending LN from ybuf.
__device__ __forceinline__ void stage_x_512(unsigned short* xs,
    const float* __restrict__ xraw, const float* __restrict__ ybuf,
    const float* __restrict__ g, const float* __restrict__ bt, int use_ln,
    float* __restrict__ xlnout){
  if (!use_ln){
    for (int i = threadIdx.x*4; i < BB*EE; i += 2048){
      float4 v = *(const float4*)(xraw + i);
      int r = i >> 9, c = i & 511;
      *(ull*)(xs + r*LDP + c) = pkbf4(v.x, v.y, v.z, v.w);
    }
  } else {
    const int lane = threadIdx.x & 63, wv = threadIdx.x >> 6;
    for (int r = wv*4; r < wv*4 + 4; ++r){
      float vals[8]; float s = 0.f, s2 = 0.f;
      #pragma unroll
      for (int j = 0; j < 8; ++j){
        float v = ybuf[r*EE + lane + j*64];
        vals[j] = v; s += v; s2 += v*v;
      }
      s = wave_sum(s); s2 = wave_sum(s2);
      float m = s * (1.f/EE);
      float inv = rsqrtf(s2*(1.f/EE) - m*m + 1e-5f);
      #pragma unroll
      for (int j = 0; j < 8; ++j){
        int c = lane + j*64;
        float v = (vals[j]-m)*inv*g[c] + bt[c];
        xs[r*LDP + c] = f_to_bf(v);
        if (xlnout) xlnout[r*EE + c] = v;
      }
    }
  }
  __syncthreads();
}

// ---------------- prologue kernels ----------------

__global__ __launch_bounds__(256) void k_init(const float* __restrict__ special,
    float* __restrict__ dseq, float* __restrict__ x,
    float* __restrict__ o2a, float* __restrict__ o2b,
    float* __restrict__ y0, float* __restrict__ y1){
  int idx = blockIdx.x*256 + threadIdx.x;
  if (idx < BB*VV){
    int b = idx >> 13, v = idx & (VV-1);
    dseq[(size_t)b*((TT+1)*VV) + (size_t)TT*VV + v] = (v == 0) ? 1.f : 0.f;
  } else if (idx < BB*VV + BB*EE){
    x[idx - BB*VV] = special[idx & (EE-1)];
  } else if (idx < BB*VV + 2*BB*EE){
    o2a[idx - BB*VV - BB*EE] = 0.f;
  } else if (idx < BB*VV + 3*BB*EE){
    o2b[idx - BB*VV - 2*BB*EE] = 0.f;
  } else if (idx < BB*VV + 4*BB*EE){
    y0[idx - BB*VV - 3*BB*EE] = 0.f;
  } else if (idx < BB*VV + 5*BB*EE){
    y1[idx - BB*VV - 4*BB*EE] = 0.f;
  }
}

__global__ __launch_bounds__(256) void k_penc(const float* __restrict__ enc,
    const float* __restrict__ w, const float* __restrict__ bias, float* __restrict__ venc){
  __shared__ unsigned short xs[BB*EE];
  __shared__ float wt[64*68];
  const int l = blockIdx.x >> 3, et = blockIdx.x & 7;
  for (int i = threadIdx.x; i < BB*EE; i += 256) xs[i] = f_to_bf(enc[i]);
  const int t = threadIdx.x, fg = t & 15, bg = t >> 4;
  const int f0 = et*64;
  const float* wl = w + (size_t)l*3*EE*EE + (size_t)(2*EE + f0)*EE;
  const float* bl = bias + l*3*EE + 2*EE + f0;
  float acc[4][2];
  #pragma unroll
  for (int i = 0; i < 4; ++i){ float bv = bl[fg*4+i]; acc[i][0] = bv; acc[i][1] = bv; }
  gemm_chunk(wl, EE, xs, wt, acc);
  #pragma unroll
  for (int i = 0; i < 4; ++i)
    #pragma unroll
    for (int j = 0; j < 2; ++j)
      venc[(size_t)l*BB*EE + (bg*2+j)*EE + f0 + fg*4 + i] = acc[i][j];
}

__global__ __launch_bounds__(256) void k_pca(const float* __restrict__ venc,
    const float* __restrict__ w, const float* __restrict__ bias, float* __restrict__ cac){
  __shared__ unsigned short xs[BB*EE];
  __shared__ float wt[64*68];
  const int l = blockIdx.x >> 3, et = blockIdx.x & 7;
  const float* vin = venc + (size_t)l*BB*EE;
  for (int i = threadIdx.x; i < BB*EE; i += 256) xs[i] = f_to_bf(vin[i]);
  const int t = threadIdx.x, fg = t & 15, bg = t >> 4;
  const int f0 = et*64;
  const float* wl = w + (size_t)l*EE*EE + (size_t)f0*EE;
  const float* bl = bias + l*EE + f0;
  float acc[4][2];
  #pragma unroll
  for (int i = 0; i < 4; ++i){ float bv = bl[fg*4+i]; acc[i][0] = bv; acc[i][1] = bv; }
  gemm_chunk(wl, EE, xs, wt, acc);
  #pragma unroll
  for (int i = 0; i < 4; ++i)
    #pragma unroll
    for (int j = 0; j < 2; ++j)
      cac[(size_t)l*BB*EE + (bg*2+j)*EE + f0 + fg*4 + i] = acc[i][j];
}

__global__ __launch_bounds__(256) void k_cvt(const float* __restrict__ s,
    unsigned short* __restrict__ d, int n4){
  int i = blockIdx.x*256 + threadIdx.x;
  if (i < n4){
    float4 v = ((const float4*)s)[i];
    ushort4 o;
    o.x = f_to_bf(v.x); o.y = f_to_bf(v.y); o.z = f_to_bf(v.z); o.w = f_to_bf(v.w);
    ((ushort4*)d)[i] = o;
  }
}

__global__ __launch_bounds__(256) void k_embT(const float* __restrict__ emb,
    unsigned short* __restrict__ eT){
  __shared__ unsigned short tl[64][68];
  const int vt = blockIdx.x >> 3, et = blockIdx.x & 7;
  const int v0 = vt*64, e0 = et*64;
  for (int i = threadIdx.x; i < 64*64; i += 256){
    int vv = i >> 6, ee = i & 63;
    tl[vv][ee] = f_to_bf(emb[(size_t)(v0+vv)*EE + e0 + ee]);
  }
  __syncthreads();
  for (int i = threadIdx.x; i < 64*64; i += 256){
    int ee = i >> 6, vv = i & 63;
    eT[(size_t)(e0+ee)*VV + v0 + vv] = tl[vv][ee];
  }
}

// ---------------- per-step kernels ----------------

// A: qkv (head h) + attention (head h) + out-projection k-split -> atomicAdd o2.
// l==0 block 0 also zeroes the gs softmax accumulators (consumed by prev SMEM).
// grid 8 x 512 threads.
__global__ __launch_bounds__(512) void k_A(
    const float* __restrict__ x, const float* __restrict__ ybuf,
    const float* __restrict__ lng, const float* __restrict__ lnb, int use_ln,
    const unsigned short* __restrict__ Wb, const float* __restrict__ bias,
    const unsigned short* __restrict__ owb_l,
    float* __restrict__ kcl, float* __restrict__ vcl,
    float* __restrict__ xln, float* __restrict__ o2,
    float* __restrict__ gs, int tpos, int tlen){
  __shared__ unsigned short xs[BB*LDP];
  __shared__ __align__(16) float qs[BB*68];
  __shared__ float att[BB*16];
  const int h = blockIdx.x;
  const int t = threadIdx.x;
  if (!use_ln && h == 0 && t < 64) gs[t] = 0.f;
  stage_x_512(xs, x, ybuf, lng, lnb, use_ln, (use_ln && h == 0) ? xln : nullptr);
  const int wv = t >> 6, lane = t & 63;
  const int lm = lane & 15, kg = lane >> 4;
  const unsigned short* b0r = xs + lm*LDP + kg*8;
  const unsigned short* b1r = xs + (lm+16)*LDP + kg*8;
  if (wv < 6){
    const int c = wv >> 1, half = wv & 1;
    #pragma unroll
    for (int ft = 0; ft < 2; ++ft){
      const int frel_t = (half*2 + ft)*16;
      const unsigned short* ar = Wb + (size_t)(c*EE + h*64 + frel_t + lm)*EE + kg*8;
      f32x4 acc0 = {0.f,0.f,0.f,0.f}, acc1 = {0.f,0.f,0.f,0.f};
      #pragma unroll 4
      for (int ks = 0; ks < 16; ++ks){
        bf16x8 a  = *reinterpret_cast<const bf16x8*>(ar + ks*32);
        bf16x8 b0 = *reinterpret_cast<const bf16x8*>(b0r + ks*32);
        bf16x8 b1 = *reinterpret_cast<const bf16x8*>(b1r + ks*32);
        acc0 = mfma16(a, b0, acc0);
        acc1 = mfma16(a, b1, acc1);
      }
      #pragma unroll
      for (int r = 0; r < 4; ++r){
        const int frel = frel_t + kg*4 + r;
        const float bv = bias[c*EE + h*64 + frel];
        float v0 = acc0[r] + bv, v1 = acc1[r] + bv;
        if (c == 0){
          qs[lm*68 + frel] = v0;
          qs[(lm+16)*68 + frel] = v1;
        } else if (c == 1){
          kcl[((lm*NHD + h)*TT + tpos)*HDD + frel] = v0;
          kcl[(((lm+16)*NHD + h)*TT + tpos)*HDD + frel] = v1;
        } else {
          vcl[((lm*NHD + h)*TT + tpos)*HDD + frel] = v0;
          vcl[(((lm+16)*NHD + h)*TT + tpos)*HDD + frel] = v1;
        }
      }
    }
  }
  __syncthreads();
  // scores: 512 (b,j) items
  {
    const int b = t >> 4, j = t & 15;
    if (j < tlen){
      const float* qrow = qs + b*68;
      const float* krow = kcl + ((b*NHD + h)*TT + j)*HDD;
      float a = 0.f;
      #pragma unroll
      for (int d = 0; d < HDD; d += 4){
        float4 qv = *(const float4*)(qrow + d);
        float4 kv = *(const float4*)(krow + d);
        a += qv.x*kv.x + qv.y*kv.y + qv.z*kv.z + qv.w*kv.w;
      }
      att[b*16 + j] = a*0.125f;
    }
  }
  __syncthreads();
  if (t < 32){
    const int b = t;
    float m = -1e30f;
    for (int j = 0; j < tlen; ++j) m = fmaxf(m, att[b*16 + j]);
    float s = 0.f;
    for (int j = 0; j < tlen; ++j) s += __expf(att[b*16 + j] - m);
    float inv = 1.f/s;
    for (int j = 0; j < tlen; ++j) att[b*16 + j] = __expf(att[b*16 + j] - m)*inv;
  }
  __syncthreads();
  // PV -> o_lds (bf16, pitch OLP); aliases qs
  unsigned short* o_lds = (unsigned short*)qs;
  {
    const int b = t >> 4, d0 = (t & 15)*4;
    float acc[4];
    #pragma unroll
    for (int i = 0; i < 4; ++i) acc[i] = 0.f;
    const float* vrow = vcl + ((b*NHD + h)*TT)*HDD + d0;
    for (int j = 0; j < tlen; ++j){
      const float a = att[b*16 + j];
      float4 v = *(const float4*)(vrow + j*HDD);
      acc[0] += a*v.x; acc[1] += a*v.y; acc[2] += a*v.z; acc[3] += a*v.w;
    }
    *(ull*)(o_lds + b*OLP + d0) = pkbf4(acc[0], acc[1], acc[2], acc[3]);
  }
  __syncthreads();
  // out-projection partial: 8 waves x 4 f-tiles
  const unsigned short* ob0 = o_lds + lm*OLP + kg*8;
  const unsigned short* ob1 = o_lds + (lm+16)*OLP + kg*8;
  #pragma unroll
  for (int ft = 0; ft < 4; ++ft){
    const int f0 = wv*64 + ft*16;
    const unsigned short* ar = owb_l + (size_t)(f0 + lm)*EE + h*HDD + kg*8;
    f32x4 a0 = {0.f,0.f,0.f,0.f}, a1 = {0.f,0.f,0.f,0.f};
    #pragma unroll
    for (int ks = 0; ks < 2; ++ks){
      bf16x8 a  = *reinterpret_cast<const bf16x8*>(ar + ks*32);
      bf16x8 x0 = *reinterpret_cast<const bf16x8*>(ob0 + ks*32);
      bf16x8 x1 = *reinterpret_cast<const bf16x8*>(ob1 + ks*32);
      a0 = mfma16(a, x0, a0);
      a1 = mfma16(a, x1, a1);
    }
    #pragma unroll
    for (int r = 0; r < 4; ++r){
      const int f = f0 + kg*4 + r;
      atomicAdd(&o2[lm*EE + f], a0[r]);
      atomicAdd(&o2[(lm+16)*EE + f], a1[r]);
    }
  }
}

// BC: stage (o2+resid+ob) -> LN1(+cac) -> LN2 -> ffn1 -> gelu -> ffn2 k-slice
// partial -> atomicAdd y. Zeroes opposite-parity y/o2; optionally zeroes x (xz).
// grid 32 x 512 threads.
__global__ __launch_bounds__(512) void k_BC(
    const float* __restrict__ o2buf, const float* __restrict__ resid,
    const float* __restrict__ ob, const float* __restrict__ cac,
    const float* __restrict__ g1, const float* __restrict__ b1g,
    const float* __restrict__ g2, const float* __restrict__ b2g,
    const float* __restrict__ b2bias,
    const unsigned short* __restrict__ w1b, const float* __restrict__ b1bias,
    const unsigned short* __restrict__ w2b,
    float* __restrict__ ycur, float* __restrict__ yzero, float* __restrict__ o2zero,
    float* __restrict__ xz){
  __shared__ unsigned short xs[BB*LDP];
  __shared__ __align__(16) float rawf[BB*RWP];
  __shared__ unsigned short Hs[BB*OLP];
  const int t = threadIdx.x, blk = blockIdx.x;
  for (int i = t*4; i < BB*EE; i += 2048){
    const int r = i >> 9, c = i & 511;
    float4 a  = *(const float4*)(o2buf + i);
    float4 rr = *(const float4*)(resid + i);
    float4 ov = *(const float4*)(ob + c);
    rawf[r*RWP + c]     = a.x + rr.x + ov.x;
    rawf[r*RWP + c + 1] = a.y + rr.y + ov.y;
    rawf[r*RWP + c + 2] = a.z + rr.z + ov.z;
    rawf[r*RWP + c + 3] = a.w + rr.w + ov.w;
  }
  __syncthreads();
  const int wv = t >> 6, lane = t & 63;
  const int lm = lane & 15, kg = lane >> 4;
  {
    const int c0 = lane*4, c1 = 256 + lane*4;
    for (int r = wv*4; r < wv*4 + 4; ++r){
      float v[8];
      *(float4*)(v+0) = *(const float4*)(rawf + r*RWP + c0);
      *(float4*)(v+4) = *(const float4*)(rawf + r*RWP + c1);
      float s = 0.f, s2 = 0.f;
      #pragma unroll
      for (int j = 0; j < 8; ++j){ s += v[j]; s2 += v[j]*v[j]; }
      s = wave_sum(s); s2 = wave_sum(s2);
      float m = s*(1.f/EE), inv = rsqrtf(s2*(1.f/EE) - m*m + 1e-5f);
      float4 ca0 = *(const float4*)(cac + (size_t)r*EE + c0);
      float4 ca1 = *(const float4*)(cac + (size_t)r*EE + c1);
      float nv[8]; float u = 0.f, u2 = 0.f;
      nv[0] = (v[0]-m)*inv*g1[c0+0] + b1g[c0+0] + ca0.x;
      nv[1] = (v[1]-m)*inv*g1[c0+1] + b1g[c0+1] + ca0.y;
      nv[2] = (v[2]-m)*inv*g1[c0+2] + b1g[c0+2] + ca0.z;
      nv[3] = (v[3]-m)*inv*g1[c0+3] + b1g[c0+3] + ca0.w;
      nv[4] = (v[4]-m)*inv*g1[c1+0] + b1g[c1+0] + ca1.x;
      nv[5] = (v[5]-m)*inv*g1[c1+1] + b1g[c1+1] + ca1.y;
      nv[6] = (v[6]-m)*inv*g1[c1+2] + b1g[c1+2] + ca1.z;
      nv[7] = (v[7]-m)*inv*g1[c1+3] + b1g[c1+3] + ca1.w;
      #pragma unroll
      for (int j = 0; j < 8; ++j){ u += nv[j]; u2 += nv[j]*nv[j]; }
      u = wave_sum(u); u2 = wave_sum(u2);
      float m2 = u*(1.f/EE), inv2 = rsqrtf(u2*(1.f/EE) - m2*m2 + 1e-5f);
      float o0 = (nv[0]-m2)*inv2*g2[c0+0] + b2g[c0+0];
      float o1 = (nv[1]-m2)*inv2*g2[c0+1] + b2g[c0+1];
      float o2v = (nv[2]-m2)*inv2*g2[c0+2] + b2g[c0+2];
      float o3 = (nv[3]-m2)*inv2*g2[c0+3] + b2g[c0+3];
      float o4 = (nv[4]-m2)*inv2*g2[c1+0] + b2g[c1+0];
      float o5 = (nv[5]-m2)*inv2*g2[c1+1] + b2g[c1+1];
      float o6 = (nv[6]-m2)*inv2*g2[c1+2] + b2g[c1+2];
      float o7 = (nv[7]-m2)*inv2*g2[c1+3] + b2g[c1+3];
      *(ull*)(xs + r*LDP + c0) = pkbf4(o0, o1, o2v, o3);
      *(ull*)(xs + r*LDP + c1) = pkbf4(o4, o5, o6, o7);
      if ((c0 >> 4) == blk){
        atomicAdd(&ycur[(size_t)r*EE + c0+0], o0 + b2bias[c0+0]);
        atomicAdd(&ycur[(size_t)r*EE + c0+1], o1 + b2bias[c0+1]);
        atomicAdd(&ycur[(size_t)r*EE + c0+2], o2v + b2bias[c0+2]);
        atomicAdd(&ycur[(size_t)r*EE + c0+3], o3 + b2bias[c0+3]);
      }
      if ((c1 >> 4) == blk){
        atomicAdd(&ycur[(size_t)r*EE + c1+0], o4 + b2bias[c1+0]);
        atomicAdd(&ycur[(size_t)r*EE + c1+1], o5 + b2bias[c1+1]);
        atomicAdd(&ycur[(size_t)r*EE + c1+2], o6 + b2bias[c1+2]);
        atomicAdd(&ycur[(size_t)r*EE + c1+3], o7 + b2bias[c1+3]);
      }
    }
  }
  __syncthreads();
  // ffn1: 8 waves = 4 f-tiles x 2 row-halves
  {
    const int ftile = wv & 3, rh = wv >> 2;
    const int f0w = blk*64 + ftile*16;
    const unsigned short* ar = w1b + (size_t)(f0w + lm)*EE + kg*8;
    const unsigned short* br = xs + (lm + rh*16)*LDP + kg*8;
    f32x4 acc = {0.f,0.f,0.f,0.f};
    #pragma unroll 4
    for (int ks = 0; ks < 16; ++ks){
      bf16x8 a = *reinterpret_cast<const bf16x8*>(ar + ks*32);
      bf16x8 b = *reinterpret_cast<const bf16x8*>(br + ks*32);
      acc = mfma16(a, b, acc);
    }
    const int fbrel = ftile*16 + kg*4;
    float hh[4];
    #pragma unroll
    for (int r = 0; r < 4; ++r){
      const float bv = b1bias[blk*64 + fbrel + r];
      float vv = acc[r] + bv;
      hh[r] = 0.5f*vv*(1.f + erff(vv*0.70710678118654752f));
    }
    *(ull*)(Hs + (lm + rh*16)*OLP + fbrel) = pkbf4(hh[0], hh[1], hh[2], hh[3]);
  }
  __syncthreads();
  // ffn2 partial over this block's 64-k slice: 8 waves x 4 e-tiles
  {
    const unsigned short* hb0 = Hs + lm*OLP + kg*8;
    const unsigned short* hb1 = Hs + (lm+16)*OLP + kg*8;
    #pragma unroll
    for (int et = 0; et < 4; ++et){
      const int e0 = (wv*4 + et)*16;
      const unsigned short* ar = w2b + (size_t)(e0 + lm)*FFD + blk*64 + kg*8;
      f32x4 a0 = {0.f,0.f,0.f,0.f}, a1 = {0.f,0.f,0.f,0.f};
      #pragma unroll
      for (int ks = 0; ks < 2; ++ks){
        bf16x8 a  = *reinterpret_cast<const bf16x8*>(ar + ks*32);
        bf16x8 h0 = *reinterpret_cast<const bf16x8*>(hb0 + ks*32);
        bf16x8 h1 = *reinterpret_cast<const bf16x8*>(hb1 + ks*32);
        a0 = mfma16(a, h0, a0);
        a1 = mfma16(a, h1, a1);
      }
      #pragma unroll
      for (int r = 0; r < 4; ++r){
        const int e = e0 + kg*4 + r;
        atomicAdd(&ycur[lm*EE + e], a0[r]);
        atomicAdd(&ycur[(lm+16)*EE + e], a1[r]);
      }
    }
  }
  // rotation zeroing: opposite-parity y and o2; optional x (after l=0 consumed it)
  yzero[blk*512 + t] = 0.f;
  o2zero[blk*512 + t] = 0.f;
  if (xz) xz[blk*512 + t] = 0.f;
}

// logits + exp: l = LN3(y1)@outw.T + outb; el=exp(l), eg=exp(l+gumbel);
// per-row partial sums -> atomicAdd gs[0..32)=sum(el), gs[32..64)=sum(eg).
// No max-subtraction: |l| <~ 3, g <~ 14 -> exp and sums well within fp32.
// grid 128 x 512.
__global__ __launch_bounds__(512) void k_logits_e(
    const float* __restrict__ ybuf, const float* __restrict__ lng, const float* __restrict__ lnb,
    const unsigned short* __restrict__ Wb, const float* __restrict__ bias,
    const float* __restrict__ gum,
    float* __restrict__ el, float* __restrict__ eg, float* __restrict__ gs){
  __shared__ unsigned short xs[BB*LDP];
  __shared__ float ls[64];
  const int t = threadIdx.x;
  if (t < 64) ls[t] = 0.f;
  stage_x_512(xs, nullptr, ybuf, lng, lnb, 1, nullptr);   // ends with syncthreads
  const int wv = t >> 6, lane = t & 63;
  const int lm = lane & 15, kg = lane >> 4;
  const int ftile = wv & 3, rh = wv >> 2;
  const int f0w = blockIdx.x*64 + ftile*16;
  const int b = lm + rh*16;
  const unsigned short* ar = Wb + (size_t)(f0w + lm)*EE + kg*8;
  const unsigned short* br = xs + b*LDP + kg*8;
  f32x4 acc = {0.f,0.f,0.f,0.f};
  #pragma unroll 4
  for (int ks = 0; ks < 16; ++ks){
    bf16x8 a = *reinterpret_cast<const bf16x8*>(ar + ks*32);
    bf16x8 bb = *reinterpret_cast<const bf16x8*>(br + ks*32);
    acc = mfma16(a, bb, acc);
  }
  const int fb = f0w + kg*4;
  float4 g4 = *(const float4*)(gum + (size_t)b*VV + fb);
  float l0 = acc[0] + bias[fb+0], l1 = acc[1] + bias[fb+1];
  float l2 = acc[2] + bias[fb+2], l3 = acc[3] + bias[fb+3];
  float e10 = __expf(l0), e11 = __expf(l1), e12 = __expf(l2), e13 = __expf(l3);
  float e20 = __expf(l0+g4.x), e21 = __expf(l1+g4.y), e22 = __expf(l2+g4.z), e23 = __expf(l3+g4.w);
  float4 ev1; ev1.x=e10; ev1.y=e11; ev1.z=e12; ev1.w=e13;
  float4 ev2; ev2.x=e20; ev2.y=e21; ev2.z=e22; ev2.w=e23;
  *(float4*)(el + (size_t)b*VV + fb) = ev1;
  *(float4*)(eg + (size_t)b*VV + fb) = ev2;
  atomicAdd(&ls[b],      e10+e11+e12+e13);
  atomicAdd(&ls[32 + b], e20+e21+e22+e23);
  __syncthreads();
  if (t < 64) atomicAdd(&gs[t], ls[t]);
}

// SMEM: fused sample-normalize + embed. sample = eg/gs2 (bf16, LDS-staged);
// x += (sample @ embT)*sqrt(E) via MFMA with eT, k-split by v-slice.
// et==0 blocks also write dseq (sample) and ddist (el/gs1).
// grid 128 = 8 e-tiles x 16 v-splits, 512 threads.
__global__ __launch_bounds__(512) void k_SMEM(
    const unsigned short* __restrict__ eT,
    const float* __restrict__ el, const float* __restrict__ eg,
    const float* __restrict__ gs,
    float* __restrict__ dseq, float* __restrict__ ddist,
    float* __restrict__ x, int step){
  __shared__ unsigned short ss[BB*LDP];
  __shared__ float rr[64];
  const int t = threadIdx.x;
  const int et = blockIdx.x & 7, v0 = (blockIdx.x >> 3)*512;
  if (t < 64) rr[t] = 1.f / gs[t];
  __syncthreads();
  // stage sample bf16 = eg * r2
  for (int i = t*4; i < BB*512; i += 2048){
    const int r = i >> 9, c = i & 511;
    float4 e4 = *(const float4*)(eg + (size_t)r*VV + v0 + c);
    const float r2v = rr[32 + r];
    *(ull*)(ss + r*LDP + c) = pkbf4(e4.x*r2v, e4.y*r2v, e4.z*r2v, e4.w*r2v);
  }
  __syncthreads();
  // embed MFMA: 8 waves = 4 e-subtiles x 2 row-halves, K=512
  const int wv = t >> 6, lane = t & 63;
  const int lm = lane & 15, kg = lane >> 4;
  const int etile = wv & 3, rh = wv >> 2;
  const int e0 = et*64 + etile*16;
  const unsigned short* ar = eT + (size_t)(e0 + lm)*VV + v0 + kg*8;
  const unsigned short* br = ss + (lm + rh*16)*LDP + kg*8;
  f32x4 acc = {0.f,0.f,0.f,0.f};
  #pragma unroll 4
  for (int ks = 0; ks < 16; ++ks){
    bf16x8 a = *reinterpret_cast<const bf16x8*>(ar + ks*32);
    bf16x8 b = *reinterpret_cast<const bf16x8*>(br + ks*32);
    acc = mfma16(a, b, acc);
  }
  #pragma unroll
  for (int r = 0; r < 4; ++r){
    const int e = e0 + kg*4 + r;
    atomicAdd(&x[(lm + rh*16)*EE + e], acc[r]*SCALE_EMB);
  }
  // output writes (once per v-slice): dseq = eg*r2, ddist = el*r1
  if (et == 0){
    for (int i = t*4; i < BB*512; i += 2048){
      const int r = i >> 9, c = i & 511;
      float4 e2 = *(const float4*)(eg + (size_t)r*VV + v0 + c);
      float4 e1 = *(const float4*)(el + (size_t)r*VV + v0 + c);
      const float r1v = rr[r], r2v = rr[32 + r];
      float4 dq; dq.x=e2.x*r2v; dq.y=e2.y*r2v; dq.z=e2.z*r2v; dq.w=e2.w*r2v;
      float4 dd; dd.x=e1.x*r1v; dd.y=e1.y*r1v; dd.z=e1.z*r1v; dd.w=e1.w*r1v;
      *(float4*)(dseq + (size_t)r*((TT+1)*VV) + (size_t)step*VV + v0 + c) = dq;
      *(float4*)(ddist + (size_t)r*VV + v0 + c) = dd;
    }
  }
}

// ---------------- host ----------------
extern "C" void kernel_launch(void* const* d_in, const int* in_sizes, int n_in,
                              void* d_out, int out_size, void* d_ws, size_t ws_size,
                              hipStream_t stream){
  (void)in_sizes; (void)n_in; (void)out_size; (void)ws_size;
  const float* enc  = (const float*)d_in[0];
  const float* spec = (const float*)d_in[1];
  const float* embw = (const float*)d_in[2];
  const float* outw = (const float*)d_in[3];
  const float* outb = (const float*)d_in[4];
  const float* gumb = (const float*)d_in[5];
  const float* saqw = (const float*)d_in[6];
  const float* saqb = (const float*)d_in[7];
  const float* saow = (const float*)d_in[8];
  const float* saob = (const float*)d_in[9];
  const float* caqw = (const float*)d_in[10];
  const float* caqb = (const float*)d_in[11];
  const float* caow = (const float*)d_in[12];
  const float* caob = (const float*)d_in[13];
  const float* l1g  = (const float*)d_in[14];
  const float* l1b  = (const float*)d_in[15];
  const float* l2g  = (const float*)d_in[16];
  const float* l2b  = (const float*)d_in[17];
  const float* l3g  = (const float*)d_in[18];
  const float* l3b  = (const float*)d_in[19];
  const float* w1   = (const float*)d_in[20];
  const float* b1   = (const float*)d_in[21];
  const float* w2   = (const float*)d_in[22];
  const float* b2   = (const float*)d_in[23];

  float* dout = (float*)d_out;
  float* dseq = dout;
  float* ddistbase = dout + (size_t)BB*(TT+1)*VV;

  unsigned char* p = (unsigned char*)d_ws;
  auto alloc = [&](size_t bytes) -> void* {
    void* r = (void*)p; p += (bytes + 255) & ~(size_t)255; return r;
  };
  float* x      = (float*)alloc(BB*EE*4);
  float* y0     = (float*)alloc(BB*EE*4);
  float* y1     = (float*)alloc(BB*EE*4);
  float* xln    = (float*)alloc(BB*EE*4);
  float* o2a    = (float*)alloc(BB*EE*4);
  float* o2b    = (float*)alloc(BB*EE*4);
  float* el     = (float*)alloc((size_t)BB*VV*4);
  float* eg     = (float*)alloc((size_t)BB*VV*4);
  float* gs     = (float*)alloc(64*4);
  float* venc   = (float*)alloc((size_t)LL*BB*EE*4);
  float* cac    = (float*)alloc((size_t)LL*BB*EE*4);
  float* kcache = (float*)alloc((size_t)LL*BB*EE*TT*4);
  float* vcache = (float*)alloc((size_t)LL*BB*EE*TT*4);
  unsigned short* wqkvb = (unsigned short*)alloc((size_t)LL*3*EE*EE*2);
  unsigned short* owb   = (unsigned short*)alloc((size_t)LL*EE*EE*2);
  unsigned short* w1b   = (unsigned short*)alloc((size_t)LL*FFD*EE*2);
  unsigned short* w2b   = (unsigned short*)alloc((size_t)LL*FFD*EE*2);
  unsigned short* outwb = (unsigned short*)alloc((size_t)VV*EE*2);
  unsigned short* eTb   = (unsigned short*)alloc((size_t)EE*VV*2);

  // prologue
  k_init<<<1344, 256, 0, stream>>>(spec, dseq, x, o2a, o2b, y0, y1);
  k_penc<<<32, 256, 0, stream>>>(enc, caqw, caqb, venc);
  k_pca<<<32, 256, 0, stream>>>(venc, caow, caob, cac);
  k_cvt<<<(LL*3*EE*EE/4 + 255)/256, 256, 0, stream>>>(saqw, wqkvb, LL*3*EE*EE/4);
  k_cvt<<<(LL*EE*EE/4 + 255)/256, 256, 0, stream>>>(saow, owb, LL*EE*EE/4);
  k_cvt<<<(LL*FFD*EE/4 + 255)/256, 256, 0, stream>>>(w1, w1b, LL*FFD*EE/4);
  k_cvt<<<(LL*FFD*EE/4 + 255)/256, 256, 0, stream>>>(w2, w2b, LL*FFD*EE/4);
  k_cvt<<<(VV*EE/4 + 255)/256, 256, 0, stream>>>(outw, outwb, VV*EE/4);
  k_embT<<<1024, 256, 0, stream>>>(embw, eTb);

  float* yb[2]  = { y0, y1 };
  float* o2p[2] = { o2a, o2b };

  // 10 launches/step: 4x(A,BC) + logits_e + SMEM
  for (int step = 0; step < TT; ++step){
    const int tpos = step, tlen = step + 1;
    for (int l = 0; l < LL; ++l){
      const int use_ln = (l > 0);
      const int par = l & 1, opp = par ^ 1;
      const float* lg = l3g + (use_ln ? (l-1)*EE : 0);
      const float* lb = l3b + (use_ln ? (l-1)*EE : 0);
      float* kcl = kcache + (size_t)l*BB*EE*TT;
      float* vcl = vcache + (size_t)l*BB*EE*TT;
      k_A<<<NHD, 512, 0, stream>>>(x, yb[opp], lg, lb, use_ln,
          wqkvb + (size_t)l*3*EE*EE, saqb + (size_t)l*3*EE,
          owb + (size_t)l*EE*EE, kcl, vcl, xln, o2p[par], gs, tpos, tlen);
      k_BC<<<32, 512, 0, stream>>>(o2p[par], use_ln ? xln : x,
          saob + (size_t)l*EE, cac + (size_t)l*BB*EE,
          l1g + l*EE, l1b + l*EE, l2g + l*EE, l2b + l*EE, b2 + l*EE,
          w1b + (size_t)l*FFD*EE, b1 + l*FFD, w2b + (size_t)l*EE*FFD,
          yb[par], yb[opp], o2p[opp], (l == 1) ? x : nullptr);
    }
    k_logits_e<<<128, 512, 0, stream>>>(yb[1], l3g + 3*EE, l3b + 3*EE, outwb, outb,
        gumb + (size_t)step*BB*VV, el, eg, gs);
    k_SMEM<<<128, 512, 0, stream>>>(eTb, el, eg, gs, dseq,
        ddistbase + (size_t)step*BB*VV, x, step);
  }
}

// Round 10
// 3827.297 us; speedup vs baseline: 1.0876x; 1.0876x over previous
//
#include <hip/hip_runtime.h>
#include <math.h>

#define BB 32
#define EE 512
#define VV 8192
#define TT 16
#define LL 4
#define FFD 2048
#define NHD 8
#define HDD 64
#define LDP 520   // padded LDS pitch (bf16 elems)
#define RWP 516   // padded LDS pitch (f32 elems)
#define OLP 72    // small-tile LDS pitch (bf16): 144B rows, 16B-aligned
#define SSP 264   // SMEM sample pitch (bf16): 528B rows
#define SCALE_EMB 22.627416997969522f

typedef __attribute__((ext_vector_type(8))) short bf16x8;
typedef __attribute__((ext_vector_type(4))) float f32x4;
typedef unsigned long long ull;

__device__ __forceinline__ f32x4 mfma16(bf16x8 a, bf16x8 b, f32x4 c){
  return __builtin_amdgcn_mfma_f32_16x16x32_bf16(a, b, c, 0, 0, 0);
}

// ---------------- helpers ----------------
__device__ __forceinline__ float wave_sum(float v){
  for (int o = 32; o; o >>= 1) v += __shfl_down(v, o);
  return __shfl(v, 0);
}
__device__ __forceinline__ unsigned short f_to_bf(float f){
  unsigned u = __float_as_uint(f);
  unsigned r = (u + 0x7fffu + ((u >> 16) & 1u)) >> 16;
  return (unsigned short)r;
}
__device__ __forceinline__ float2 bf2_to_f2(const unsigned short* p){
  unsigned u = *(const unsigned*)p;
  float2 r;
  r.x = __uint_as_float(u << 16);
  r.y = __uint_as_float(u & 0xffff0000u);
  return r;
}
union UF { ull u; unsigned short s[4]; };
__device__ __forceinline__ ull pkbf4(float a, float b, float c, float d){
  UF x; x.s[0] = f_to_bf(a); x.s[1] = f_to_bf(b); x.s[2] = f_to_bf(c); x.s[3] = f_to_bf(d); return x.u;
}

// fp32 VALU GEMM core (one-off prologue kernels k_penc/k_pca)
__device__ __forceinline__ void gemm_chunk(const float* __restrict__ wrow0, int ldw,
    const unsigned short* xs, float* wt, float acc[4][2]){
  const int t = threadIdx.x, fg = t & 15, bg = t >> 4;
  #pragma unroll 1
  for (int c = 0; c < 8; ++c){
    const int k0 = c*64;
    __syncthreads();
    {
      int i = t*4;
      #pragma unroll
      for (int p = 0; p < 4; ++p, i += 1024){
        const int fr = i >> 6, kk = i & 63;
        float4 v = *(const float4*)(wrow0 + (size_t)fr*ldw + k0 + kk);
        wt[(kk+0)*68 + fr] = v.x;
        wt[(kk+1)*68 + fr] = v.y;
        wt[(kk+2)*68 + fr] = v.z;
        wt[(kk+3)*68 + fr] = v.w;
      }
    }
    __syncthreads();
    const unsigned short* xr0 = xs + (bg*2)*EE + k0;
    const unsigned short* xr1 = xr0 + EE;
    #pragma unroll 8
    for (int k = 0; k < 64; k += 2){
      float w0[4], w1[4];
      *(float4*)w0 = *(const float4*)(wt + (k+0)*68 + fg*4);
      *(float4*)w1 = *(const float4*)(wt + (k+1)*68 + fg*4);
      float2 xv0 = bf2_to_f2(xr0 + k);
      float2 xv1 = bf2_to_f2(xr1 + k);
      #pragma unroll
      for (int i = 0; i < 4; ++i){
        acc[i][0] += w0[i]*xv0.x + w1[i]*xv0.y;
        acc[i][1] += w0[i]*xv1.x + w1[i]*xv1.y;
      }
    }
  }
}

// Stage 16 rows [rb, rb+16) of [B,E] into padded-LDS bf16 with 512 threads;
// optional pending LN from ybuf; optional LN'd fp32 rows to xlnout.
__device__ __forceinline__ void stage_half_512(unsigned short* xs, int rb,
    const float* __restrict__ xraw, const float* __restrict__ ybuf,
    const float* __restrict__ g, const float* __restrict__ bt, int use_ln,
    float* __restrict__ xlnout){
  if (!use_ln){
    for (int i = threadIdx.x*4; i < 16*EE; i += 2048){
      float4 v = *(const float4*)(xraw + (size_t)rb*EE + i);
      int r = i >> 9, c = i & 511;
      *(ull*)(xs + r*LDP + c) = pkbf4(v.x, v.y, v.z, v.w);
    }
  } else {
    const int lane = threadIdx.x & 63, wv = threadIdx.x >> 6;
    for (int r = wv*2; r < wv*2 + 2; ++r){
      const float* yr = ybuf + (size_t)(rb + r)*EE;
      float vals[8]; float s = 0.f, s2 = 0.f;
      #pragma unroll
      for (int j = 0; j < 8; ++j){
        float v = yr[lane + j*64];
        vals[j] = v; s += v; s2 += v*v;
      }
      s = wave_sum(s); s2 = wave_sum(s2);
      float m = s * (1.f/EE);
      float inv = rsqrtf(s2*(1.f/EE) - m*m + 1e-5f);
      #pragma unroll
      for (int j = 0; j < 8; ++j){
        int c = lane + j*64;
        float v = (vals[j]-m)*inv*g[c] + bt[c];
        xs[r*LDP + c] = f_to_bf(v);
        if (xlnout) xlnout[(size_t)(rb + r)*EE + c] = v;
      }
    }
  }
  __syncthreads();
}

// Stage all 32 rows with pending LN using 256 threads (4 waves x 8 rows).
__device__ __forceinline__ void stage_ln_256(unsigned short* xs,
    const float* __restrict__ ybuf, const float* __restrict__ g,
    const float* __restrict__ bt){
  const int lane = threadIdx.x & 63, wv = threadIdx.x >> 6;
  for (int r = wv*8; r < wv*8 + 8; ++r){
    float vals[8]; float s = 0.f, s2 = 0.f;
    #pragma unroll
    for (int j = 0; j < 8; ++j){
      float v = ybuf[(size_t)r*EE + lane + j*64];
      vals[j] = v; s += v; s2 += v*v;
    }
    s = wave_sum(s); s2 = wave_sum(s2);
    float m = s * (1.f/EE);
    float inv = rsqrtf(s2*(1.f/EE) - m*m + 1e-5f);
    #pragma unroll
    for (int j = 0; j < 8; ++j){
      int c = lane + j*64;
      xs[r*LDP + c] = f_to_bf((vals[j]-m)*inv*g[c] + bt[c]);
    }
  }
  __syncthreads();
}

// ---------------- prologue kernels ----------------

__global__ __launch_bounds__(256) void k_init(const float* __restrict__ special,
    float* __restrict__ dseq, float* __restrict__ x,
    float* __restrict__ o2a, float* __restrict__ o2b,
    float* __restrict__ y0, float* __restrict__ y1){
  int idx = blockIdx.x*256 + threadIdx.x;
  if (idx < BB*VV){
    int b = idx >> 13, v = idx & (VV-1);
    dseq[(size_t)b*((TT+1)*VV) + (size_t)TT*VV + v] = (v == 0) ? 1.f : 0.f;
  } else if (idx < BB*VV + BB*EE){
    x[idx - BB*VV] = special[idx & (EE-1)];
  } else if (idx < BB*VV + 2*BB*EE){
    o2a[idx - BB*VV - BB*EE] = 0.f;
  } else if (idx < BB*VV + 3*BB*EE){
    o2b[idx - BB*VV - 2*BB*EE] = 0.f;
  } else if (idx < BB*VV + 4*BB*EE){
    y0[idx - BB*VV - 3*BB*EE] = 0.f;
  } else if (idx < BB*VV + 5*BB*EE){
    y1[idx - BB*VV - 4*BB*EE] = 0.f;
  }
}

__global__ __launch_bounds__(256) void k_penc(const float* __restrict__ enc,
    const float* __restrict__ w, const float* __restrict__ bias, float* __restrict__ venc){
  __shared__ unsigned short xs[BB*EE];
  __shared__ float wt[64*68];
  const int l = blockIdx.x >> 3, et = blockIdx.x & 7;
  for (int i = threadIdx.x; i < BB*EE; i += 256) xs[i] = f_to_bf(enc[i]);
  const int t = threadIdx.x, fg = t & 15, bg = t >> 4;
  const int f0 = et*64;
  const float* wl = w + (size_t)l*3*EE*EE + (size_t)(2*EE + f0)*EE;
  const float* bl = bias + l*3*EE + 2*EE + f0;
  float acc[4][2];
  #pragma unroll
  for (int i = 0; i < 4; ++i){ float bv = bl[fg*4+i]; acc[i][0] = bv; acc[i][1] = bv; }
  gemm_chunk(wl, EE, xs, wt, acc);
  #pragma unroll
  for (int i = 0; i < 4; ++i)
    #pragma unroll
    for (int j = 0; j < 2; ++j)
      venc[(size_t)l*BB*EE + (bg*2+j)*EE + f0 + fg*4 + i] = acc[i][j];
}

__global__ __launch_bounds__(256) void k_pca(const float* __restrict__ venc,
    const float* __restrict__ w, const float* __restrict__ bias, float* __restrict__ cac){
  __shared__ unsigned short xs[BB*EE];
  __shared__ float wt[64*68];
  const int l = blockIdx.x >> 3, et = blockIdx.x & 7;
  const float* vin = venc + (size_t)l*BB*EE;
  for (int i = threadIdx.x; i < BB*EE; i += 256) xs[i] = f_to_bf(vin[i]);
  const int t = threadIdx.x, fg = t & 15, bg = t >> 4;
  const int f0 = et*64;
  const float* wl = w + (size_t)l*EE*EE + (size_t)f0*EE;
  const float* bl = bias + l*EE + f0;
  float acc[4][2];
  #pragma unroll
  for (int i = 0; i < 4; ++i){ float bv = bl[fg*4+i]; acc[i][0] = bv; acc[i][1] = bv; }
  gemm_chunk(wl, EE, xs, wt, acc);
  #pragma unroll
  for (int i = 0; i < 4; ++i)
    #pragma unroll
    for (int j = 0; j < 2; ++j)
      cac[(size_t)l*BB*EE + (bg*2+j)*EE + f0 + fg*4 + i] = acc[i][j];
}

__global__ __launch_bounds__(256) void k_cvt(const float* __restrict__ s,
    unsigned short* __restrict__ d, int n4){
  int i = blockIdx.x*256 + threadIdx.x;
  if (i < n4){
    float4 v = ((const float4*)s)[i];
    ushort4 o;
    o.x = f_to_bf(v.x); o.y = f_to_bf(v.y); o.z = f_to_bf(v.z); o.w = f_to_bf(v.w);
    ((ushort4*)d)[i] = o;
  }
}

__global__ __launch_bounds__(256) void k_embT(const float* __restrict__ emb,
    unsigned short* __restrict__ eT){
  __shared__ unsigned short tl[64][68];
  const int vt = blockIdx.x >> 3, et = blockIdx.x & 7;
  const int v0 = vt*64, e0 = et*64;
  for (int i = threadIdx.x; i < 64*64; i += 256){
    int vv = i >> 6, ee = i & 63;
    tl[vv][ee] = f_to_bf(emb[(size_t)(v0+vv)*EE + e0 + ee]);
  }
  __syncthreads();
  for (int i = threadIdx.x; i < 64*64; i += 256){
    int ee = i >> 6, vv = i & 63;
    eT[(size_t)(e0+ee)*VV + v0 + vv] = tl[vv][ee];
  }
}

// ---------------- per-step kernels ----------------

// A: block (h, bhalf) computes qkv + attention + out-proj partial for head h,
// batch rows [bh*16, bh*16+16). Weights read 2x (redundant across bhalves);
// per-block serial work halves; 16 CUs active. grid 16 x 512.
__global__ __launch_bounds__(512) void k_A(
    const float* __restrict__ x, const float* __restrict__ ybuf,
    const float* __restrict__ lng, const float* __restrict__ lnb, int use_ln,
    const unsigned short* __restrict__ Wb, const float* __restrict__ bias,
    const unsigned short* __restrict__ owb_l,
    float* __restrict__ kcl, float* __restrict__ vcl,
    float* __restrict__ xln, float* __restrict__ o2,
    float* __restrict__ gs, int tpos, int tlen){
  __shared__ unsigned short xs[16*LDP];
  __shared__ __align__(16) float qs[16*68];
  __shared__ float att[16*16];
  const int h = blockIdx.x >> 1, bh = blockIdx.x & 1, rb = bh*16;
  const int t = threadIdx.x;
  if (!use_ln && blockIdx.x == 0 && t < 64) gs[t] = 0.f;
  stage_half_512(xs, rb, x, ybuf, lng, lnb, use_ln, (use_ln && h == 0) ? xln : nullptr);
  const int wv = t >> 6, lane = t & 63;
  const int lm = lane & 15, kg = lane >> 4;
  const unsigned short* br = xs + lm*LDP + kg*8;   // rows rb+lm (local lm)
  if (wv < 6){
    const int c = wv >> 1, half = wv & 1;
    #pragma unroll
    for (int ft = 0; ft < 2; ++ft){
      const int frel_t = (half*2 + ft)*16;
      const unsigned short* ar = Wb + (size_t)(c*EE + h*64 + frel_t + lm)*EE + kg*8;
      f32x4 acc = {0.f,0.f,0.f,0.f};
      #pragma unroll 4
      for (int ks = 0; ks < 16; ++ks){
        bf16x8 a = *reinterpret_cast<const bf16x8*>(ar + ks*32);
        bf16x8 b = *reinterpret_cast<const bf16x8*>(br + ks*32);
        acc = mfma16(a, b, acc);
      }
      #pragma unroll
      for (int r = 0; r < 4; ++r){
        const int frel = frel_t + kg*4 + r;
        const float v0 = acc[r] + bias[c*EE + h*64 + frel];
        if (c == 0){
          qs[lm*68 + frel] = v0;
        } else if (c == 1){
          kcl[(((rb+lm)*NHD + h)*TT + tpos)*HDD + frel] = v0;
        } else {
          vcl[(((rb+lm)*NHD + h)*TT + tpos)*HDD + frel] = v0;
        }
      }
    }
  }
  __syncthreads();
  // scores: 16 rows x 16 j = 256 items
  if (t < 256){
    const int bl = t >> 4, j = t & 15;
    if (j < tlen){
      const float* qrow = qs + bl*68;
      const float* krow = kcl + (((rb+bl)*NHD + h)*TT + j)*HDD;
      float a = 0.f;
      #pragma unroll
      for (int d = 0; d < HDD; d += 4){
        float4 qv = *(const float4*)(qrow + d);
        float4 kv = *(const float4*)(krow + d);
        a += qv.x*kv.x + qv.y*kv.y + qv.z*kv.z + qv.w*kv.w;
      }
      att[bl*16 + j] = a*0.125f;
    }
  }
  __syncthreads();
  if (t < 16){
    const int bl = t;
    float m = -1e30f;
    for (int j = 0; j < tlen; ++j) m = fmaxf(m, att[bl*16 + j]);
    float s = 0.f;
    for (int j = 0; j < tlen; ++j) s += __expf(att[bl*16 + j] - m);
    float inv = 1.f/s;
    for (int j = 0; j < tlen; ++j) att[bl*16 + j] = __expf(att[bl*16 + j] - m)*inv;
  }
  __syncthreads();
  // PV -> o_lds (bf16, pitch OLP); aliases qs
  unsigned short* o_lds = (unsigned short*)qs;
  if (t < 256){
    const int bl = t >> 4, d0 = (t & 15)*4;
    float acc[4];
    #pragma unroll
    for (int i = 0; i < 4; ++i) acc[i] = 0.f;
    const float* vrow = vcl + (((rb+bl)*NHD + h)*TT)*HDD + d0;
    for (int j = 0; j < tlen; ++j){
      const float a = att[bl*16 + j];
      float4 v = *(const float4*)(vrow + j*HDD);
      acc[0] += a*v.x; acc[1] += a*v.y; acc[2] += a*v.z; acc[3] += a*v.w;
    }
    *(ull*)(o_lds + bl*OLP + d0) = pkbf4(acc[0], acc[1], acc[2], acc[3]);
  }
  __syncthreads();
  // out-projection partial (rows rb..rb+16): 8 waves x 4 f-tiles
  const unsigned short* ob = o_lds + lm*OLP + kg*8;
  #pragma unroll
  for (int ft = 0; ft < 4; ++ft){
    const int f0 = wv*64 + ft*16;
    const unsigned short* ar = owb_l + (size_t)(f0 + lm)*EE + h*HDD + kg*8;
    f32x4 a0 = {0.f,0.f,0.f,0.f};
    #pragma unroll
    for (int ks = 0; ks < 2; ++ks){
      bf16x8 a  = *reinterpret_cast<const bf16x8*>(ar + ks*32);
      bf16x8 x0 = *reinterpret_cast<const bf16x8*>(ob + ks*32);
      a0 = mfma16(a, x0, a0);
    }
    #pragma unroll
    for (int r = 0; r < 4; ++r){
      const int f = f0 + kg*4 + r;
      atomicAdd(&o2[(rb+lm)*EE + f], a0[r]);
    }
  }
}

// BC: stage (o2+resid+ob) -> LN1(+cac) -> LN2 -> ffn1 -> gelu -> ffn2 k-slice
// partial -> atomicAdd y. Zeroes opposite-parity y/o2; optionally zeroes x (xz).
// grid 32 x 512 threads.
__global__ __launch_bounds__(512) void k_BC(
    const float* __restrict__ o2buf, const float* __restrict__ resid,
    const float* __restrict__ ob, const float* __restrict__ cac,
    const float* __restrict__ g1, const float* __restrict__ b1g,
    const float* __restrict__ g2, const float* __restrict__ b2g,
    const float* __restrict__ b2bias,
    const unsigned short* __restrict__ w1b, const float* __restrict__ b1bias,
    const unsigned short* __restrict__ w2b,
    float* __restrict__ ycur, float* __restrict__ yzero, float* __restrict__ o2zero,
    float* __restrict__ xz){
  __shared__ unsigned short xs[BB*LDP];
  __shared__ __align__(16) float rawf[BB*RWP];
  __shared__ unsigned short Hs[BB*OLP];
  const int t = threadIdx.x, blk = blockIdx.x;
  for (int i = t*4; i < BB*EE; i += 2048){
    const int r = i >> 9, c = i & 511;
    float4 a  = *(const float4*)(o2buf + i);
    float4 rr = *(const float4*)(resid + i);
    float4 ov = *(const float4*)(ob + c);
    rawf[r*RWP + c]     = a.x + rr.x + ov.x;
    rawf[r*RWP + c + 1] = a.y + rr.y + ov.y;
    rawf[r*RWP + c + 2] = a.z + rr.z + ov.z;
    rawf[r*RWP + c + 3] = a.w + rr.w + ov.w;
  }
  __syncthreads();
  const int wv = t >> 6, lane = t & 63;
  const int lm = lane & 15, kg = lane >> 4;
  {
    const int c0 = lane*4, c1 = 256 + lane*4;
    for (int r = wv*4; r < wv*4 + 4; ++r){
      float v[8];
      *(float4*)(v+0) = *(const float4*)(rawf + r*RWP + c0);
      *(float4*)(v+4) = *(const float4*)(rawf + r*RWP + c1);
      float s = 0.f, s2 = 0.f;
      #pragma unroll
      for (int j = 0; j < 8; ++j){ s += v[j]; s2 += v[j]*v[j]; }
      s = wave_sum(s); s2 = wave_sum(s2);
      float m = s*(1.f/EE), inv = rsqrtf(s2*(1.f/EE) - m*m + 1e-5f);
      float4 ca0 = *(const float4*)(cac + (size_t)r*EE + c0);
      float4 ca1 = *(const float4*)(cac + (size_t)r*EE + c1);
      float nv[8]; float u = 0.f, u2 = 0.f;
      nv[0] = (v[0]-m)*inv*g1[c0+0] + b1g[c0+0] + ca0.x;
      nv[1] = (v[1]-m)*inv*g1[c0+1] + b1g[c0+1] + ca0.y;
      nv[2] = (v[2]-m)*inv*g1[c0+2] + b1g[c0+2] + ca0.z;
      nv[3] = (v[3]-m)*inv*g1[c0+3] + b1g[c0+3] + ca0.w;
      nv[4] = (v[4]-m)*inv*g1[c1+0] + b1g[c1+0] + ca1.x;
      nv[5] = (v[5]-m)*inv*g1[c1+1] + b1g[c1+1] + ca1.y;
      nv[6] = (v[6]-m)*inv*g1[c1+2] + b1g[c1+2] + ca1.z;
      nv[7] = (v[7]-m)*inv*g1[c1+3] + b1g[c1+3] + ca1.w;
      #pragma unroll
      for (int j = 0; j < 8; ++j){ u += nv[j]; u2 += nv[j]*nv[j]; }
      u = wave_sum(u); u2 = wave_sum(u2);
      float m2 = u*(1.f/EE), inv2 = rsqrtf(u2*(1.f/EE) - m2*m2 + 1e-5f);
      float o0 = (nv[0]-m2)*inv2*g2[c0+0] + b2g[c0+0];
      float o1 = (nv[1]-m2)*inv2*g2[c0+1] + b2g[c0+1];
      float o2v = (nv[2]-m2)*inv2*g2[c0+2] + b2g[c0+2];
      float o3 = (nv[3]-m2)*inv2*g2[c0+3] + b2g[c0+3];
      float o4 = (nv[4]-m2)*inv2*g2[c1+0] + b2g[c1+0];
      float o5 = (nv[5]-m2)*inv2*g2[c1+1] + b2g[c1+1];
      float o6 = (nv[6]-m2)*inv2*g2[c1+2] + b2g[c1+2];
      float o7 = (nv[7]-m2)*inv2*g2[c1+3] + b2g[c1+3];
      *(ull*)(xs + r*LDP + c0) = pkbf4(o0, o1, o2v, o3);
      *(ull*)(xs + r*LDP + c1) = pkbf4(o4, o5, o6, o7);
      if ((c0 >> 4) == blk){
        atomicAdd(&ycur[(size_t)r*EE + c0+0], o0 + b2bias[c0+0]);
        atomicAdd(&ycur[(size_t)r*EE + c0+1], o1 + b2bias[c0+1]);
        atomicAdd(&ycur[(size_t)r*EE + c0+2], o2v + b2bias[c0+2]);
        atomicAdd(&ycur[(size_t)r*EE + c0+3], o3 + b2bias[c0+3]);
      }
      if ((c1 >> 4) == blk){
        atomicAdd(&ycur[(size_t)r*EE + c1+0], o4 + b2bias[c1+0]);
        atomicAdd(&ycur[(size_t)r*EE + c1+1], o5 + b2bias[c1+1]);
        atomicAdd(&ycur[(size_t)r*EE + c1+2], o6 + b2bias[c1+2]);
        atomicAdd(&ycur[(size_t)r*EE + c1+3], o7 + b2bias[c1+3]);
      }
    }
  }
  __syncthreads();
  // ffn1: 8 waves = 4 f-tiles x 2 row-halves
  {
    const int ftile = wv & 3, rh = wv >> 2;
    const int f0w = blk*64 + ftile*16;
    const unsigned short* ar = w1b + (size_t)(f0w + lm)*EE + kg*8;
    const unsigned short* br = xs + (lm + rh*16)*LDP + kg*8;
    f32x4 acc = {0.f,0.f,0.f,0.f};
    #pragma unroll 4
    for (int ks = 0; ks < 16; ++ks){
      bf16x8 a = *reinterpret_cast<const bf16x8*>(ar + ks*32);
      bf16x8 b = *reinterpret_cast<const bf16x8*>(br + ks*32);
      acc = mfma16(a, b, acc);
    }
    const int fbrel = ftile*16 + kg*4;
    float hh[4];
    #pragma unroll
    for (int r = 0; r < 4; ++r){
      const float bv = b1bias[blk*64 + fbrel + r];
      float vv = acc[r] + bv;
      hh[r] = 0.5f*vv*(1.f + erff(vv*0.70710678118654752f));
    }
    *(ull*)(Hs + (lm + rh*16)*OLP + fbrel) = pkbf4(hh[0], hh[1], hh[2], hh[3]);
  }
  __syncthreads();
  // ffn2 partial over this block's 64-k slice: 8 waves x 4 e-tiles
  {
    const unsigned short* hb0 = Hs + lm*OLP + kg*8;
    const unsigned short* hb1 = Hs + (lm+16)*OLP + kg*8;
    #pragma unroll
    for (int et = 0; et < 4; ++et){
      const int e0 = (wv*4 + et)*16;
      const unsigned short* ar = w2b + (size_t)(e0 + lm)*FFD + blk*64 + kg*8;
      f32x4 a0 = {0.f,0.f,0.f,0.f}, a1 = {0.f,0.f,0.f,0.f};
      #pragma unroll
      for (int ks = 0; ks < 2; ++ks){
        bf16x8 a  = *reinterpret_cast<const bf16x8*>(ar + ks*32);
        bf16x8 h0 = *reinterpret_cast<const bf16x8*>(hb0 + ks*32);
        bf16x8 h1 = *reinterpret_cast<const bf16x8*>(hb1 + ks*32);
        a0 = mfma16(a, h0, a0);
        a1 = mfma16(a, h1, a1);
      }
      #pragma unroll
      for (int r = 0; r < 4; ++r){
        const int e = e0 + kg*4 + r;
        atomicAdd(&ycur[lm*EE + e], a0[r]);
        atomicAdd(&ycur[(lm+16)*EE + e], a1[r]);
      }
    }
  }
  yzero[blk*512 + t] = 0.f;
  o2zero[blk*512 + t] = 0.f;
  if (xz) xz[blk*512 + t] = 0.f;
}

// logits + exp (no max-subtraction; |l|<~3, g<~14 -> fp32-safe).
// grid 256 x 256: block = 32 features; 4 waves = 2 f-tiles x 2 row-halves.
__global__ __launch_bounds__(256) void k_logits_e(
    const float* __restrict__ ybuf, const float* __restrict__ lng, const float* __restrict__ lnb,
    const unsigned short* __restrict__ Wb, const float* __restrict__ bias,
    const float* __restrict__ gum,
    float* __restrict__ el, float* __restrict__ eg, float* __restrict__ gs){
  __shared__ unsigned short xs[BB*LDP];
  __shared__ float ls[64];
  const int t = threadIdx.x;
  if (t < 64) ls[t] = 0.f;
  stage_ln_256(xs, ybuf, lng, lnb);   // ends with syncthreads
  const int wv = t >> 6, lane = t & 63;
  const int lm = lane & 15, kg = lane >> 4;
  const int ftile = wv & 1, rh = wv >> 1;
  const int f0w = blockIdx.x*32 + ftile*16;
  const int b = lm + rh*16;
  const unsigned short* ar = Wb + (size_t)(f0w + lm)*EE + kg*8;
  const unsigned short* br = xs + b*LDP + kg*8;
  f32x4 acc = {0.f,0.f,0.f,0.f};
  #pragma unroll 4
  for (int ks = 0; ks < 16; ++ks){
    bf16x8 a = *reinterpret_cast<const bf16x8*>(ar + ks*32);
    bf16x8 bb = *reinterpret_cast<const bf16x8*>(br + ks*32);
    acc = mfma16(a, bb, acc);
  }
  const int fb = f0w + kg*4;
  float4 g4 = *(const float4*)(gum + (size_t)b*VV + fb);
  float l0 = acc[0] + bias[fb+0], l1 = acc[1] + bias[fb+1];
  float l2 = acc[2] + bias[fb+2], l3 = acc[3] + bias[fb+3];
  float e10 = __expf(l0), e11 = __expf(l1), e12 = __expf(l2), e13 = __expf(l3);
  float e20 = __expf(l0+g4.x), e21 = __expf(l1+g4.y), e22 = __expf(l2+g4.z), e23 = __expf(l3+g4.w);
  float4 ev1; ev1.x=e10; ev1.y=e11; ev1.z=e12; ev1.w=e13;
  float4 ev2; ev2.x=e20; ev2.y=e21; ev2.z=e22; ev2.w=e23;
  *(float4*)(el + (size_t)b*VV + fb) = ev1;
  *(float4*)(eg + (size_t)b*VV + fb) = ev2;
  atomicAdd(&ls[b],      e10+e11+e12+e13);
  atomicAdd(&ls[32 + b], e20+e21+e22+e23);
  __syncthreads();
  if (t < 64) atomicAdd(&gs[t], ls[t]);
}

// SMEM: fused sample-normalize + embed. grid 256 = 8 e-tiles x 32 v-slices
// (K=256), 256 threads (4 waves = 2 e-subtile-pairs x 2 row-halves).
// et==0 blocks also write dseq (sample) and ddist (el/gs1) for their v-slice.
__global__ __launch_bounds__(256) void k_SMEM(
    const unsigned short* __restrict__ eT,
    const float* __restrict__ el, const float* __restrict__ eg,
    const float* __restrict__ gs,
    float* __restrict__ dseq, float* __restrict__ ddist,
    float* __restrict__ x, int step){
  __shared__ unsigned short ss[BB*SSP];
  __shared__ float rr[64];
  const int t = threadIdx.x;
  const int et = blockIdx.x & 7, v0 = (blockIdx.x >> 3)*256;
  if (t < 64) rr[t] = 1.f / gs[t];
  __syncthreads();
  // stage sample bf16 = eg * r2 (32 rows x 256 cols)
  for (int i = t*4; i < BB*256; i += 1024){
    const int r = i >> 8, c = i & 255;
    float4 e4 = *(const float4*)(eg + (size_t)r*VV + v0 + c);
    const float r2v = rr[32 + r];
    *(ull*)(ss + r*SSP + c) = pkbf4(e4.x*r2v, e4.y*r2v, e4.z*r2v, e4.w*r2v);
  }
  __syncthreads();
  // embed MFMA: 4 waves; each wave 2 e-subtiles; K=256 (8 ks)
  const int wv = t >> 6, lane = t & 63;
  const int lm = lane & 15, kg = lane >> 4;
  const int rh = wv >> 1;
  const unsigned short* br = ss + (lm + rh*16)*SSP + kg*8;
  #pragma unroll
  for (int ft = 0; ft < 2; ++ft){
    const int etile = (wv & 1)*2 + ft;
    const int e0 = et*64 + etile*16;
    const unsigned short* ar = eT + (size_t)(e0 + lm)*VV + v0 + kg*8;
    f32x4 acc = {0.f,0.f,0.f,0.f};
    #pragma unroll 4
    for (int ks = 0; ks < 8; ++ks){
      bf16x8 a = *reinterpret_cast<const bf16x8*>(ar + ks*32);
      bf16x8 b = *reinterpret_cast<const bf16x8*>(br + ks*32);
      acc = mfma16(a, b, acc);
    }
    #pragma unroll
    for (int r = 0; r < 4; ++r){
      const int e = e0 + kg*4 + r;
      atomicAdd(&x[(lm + rh*16)*EE + e], acc[r]*SCALE_EMB);
    }
  }
  // output writes (once per v-slice): dseq = eg*r2, ddist = el*r1
  if (et == 0){
    for (int i = t*4; i < BB*256; i += 1024){
      const int r = i >> 8, c = i & 255;
      float4 e2 = *(const float4*)(eg + (size_t)r*VV + v0 + c);
      float4 e1 = *(const float4*)(el + (size_t)r*VV + v0 + c);
      const float r1v = rr[r], r2v = rr[32 + r];
      float4 dq; dq.x=e2.x*r2v; dq.y=e2.y*r2v; dq.z=e2.z*r2v; dq.w=e2.w*r2v;
      float4 dd; dd.x=e1.x*r1v; dd.y=e1.y*r1v; dd.z=e1.z*r1v; dd.w=e1.w*r1v;
      *(float4*)(dseq + (size_t)r*((TT+1)*VV) + (size_t)step*VV + v0 + c) = dq;
      *(float4*)(ddist + (size_t)r*VV + v0 + c) = dd;
    }
  }
}

// ---------------- host ----------------
extern "C" void kernel_launch(void* const* d_in, const int* in_sizes, int n_in,
                              void* d_out, int out_size, void* d_ws, size_t ws_size,
                              hipStream_t stream){
  (void)in_sizes; (void)n_in; (void)out_size; (void)ws_size;
  const float* enc  = (const float*)d_in[0];
  const float* spec = (const float*)d_in[1];
  const float* embw = (const float*)d_in[2];
  const float* outw = (const float*)d_in[3];
  const float* outb = (const float*)d_in[4];
  const float* gumb = (const float*)d_in[5];
  const float* saqw = (const float*)d_in[6];
  const float* saqb = (const float*)d_in[7];
  const float* saow = (const float*)d_in[8];
  const float* saob = (const float*)d_in[9];
  const float* caqw = (const float*)d_in[10];
  const float* caqb = (const float*)d_in[11];
  const float* caow = (const float*)d_in[12];
  const float* caob = (const float*)d_in[13];
  const float* l1g  = (const float*)d_in[14];
  const float* l1b  = (const float*)d_in[15];
  const float* l2g  = (const float*)d_in[16];
  const float* l2b  = (const float*)d_in[17];
  const float* l3g  = (const float*)d_in[18];
  const float* l3b  = (const float*)d_in[19];
  const float* w1   = (const float*)d_in[20];
  const float* b1   = (const float*)d_in[21];
  const float* w2   = (const float*)d_in[22];
  const float* b2   = (const float*)d_in[23];

  float* dout = (float*)d_out;
  float* dseq = dout;
  float* ddistbase = dout + (size_t)BB*(TT+1)*VV;

  unsigned char* p = (unsigned char*)d_ws;
  auto alloc = [&](size_t bytes) -> void* {
    void* r = (void*)p; p += (bytes + 255) & ~(size_t)255; return r;
  };
  float* x      = (float*)alloc(BB*EE*4);
  float* y0     = (float*)alloc(BB*EE*4);
  float* y1     = (float*)alloc(BB*EE*4);
  float* xln    = (float*)alloc(BB*EE*4);
  float* o2a    = (float*)alloc(BB*EE*4);
  float* o2b    = (float*)alloc(BB*EE*4);
  float* el     = (float*)alloc((size_t)BB*VV*4);
  float* eg     = (float*)alloc((size_t)BB*VV*4);
  float* gs     = (float*)alloc(64*4);
  float* venc   = (float*)alloc((size_t)LL*BB*EE*4);
  float* cac    = (float*)alloc((size_t)LL*BB*EE*4);
  float* kcache = (float*)alloc((size_t)LL*BB*EE*TT*4);
  float* vcache = (float*)alloc((size_t)LL*BB*EE*TT*4);
  unsigned short* wqkvb = (unsigned short*)alloc((size_t)LL*3*EE*EE*2);
  unsigned short* owb   = (unsigned short*)alloc((size_t)LL*EE*EE*2);
  unsigned short* w1b   = (unsigned short*)alloc((size_t)LL*FFD*EE*2);
  unsigned short* w2b   = (unsigned short*)alloc((size_t)LL*FFD*EE*2);
  unsigned short* outwb = (unsigned short*)alloc((size_t)VV*EE*2);
  unsigned short* eTb   = (unsigned short*)alloc((size_t)EE*VV*2);

  // prologue
  k_init<<<1344, 256, 0, stream>>>(spec, dseq, x, o2a, o2b, y0, y1);
  k_penc<<<32, 256, 0, stream>>>(enc, caqw, caqb, venc);
  k_pca<<<32, 256, 0, stream>>>(venc, caow, caob, cac);
  k_cvt<<<(LL*3*EE*EE/4 + 255)/256, 256, 0, stream>>>(saqw, wqkvb, LL*3*EE*EE/4);
  k_cvt<<<(LL*EE*EE/4 + 255)/256, 256, 0, stream>>>(saow, owb, LL*EE*EE/4);
  k_cvt<<<(LL*FFD*EE/4 + 255)/256, 256, 0, stream>>>(w1, w1b, LL*FFD*EE/4);
  k_cvt<<<(LL*FFD*EE/4 + 255)/256, 256, 0, stream>>>(w2, w2b, LL*FFD*EE/4);
  k_cvt<<<(VV*EE/4 + 255)/256, 256, 0, stream>>>(outw, outwb, VV*EE/4);
  k_embT<<<1024, 256, 0, stream>>>(embw, eTb);

  float* yb[2]  = { y0, y1 };
  float* o2p[2] = { o2a, o2b };

  // 10 launches/step: 4x(A,BC) + logits_e + SMEM
  for (int step = 0; step < TT; ++step){
    const int tpos = step, tlen = step + 1;
    for (int l = 0; l < LL; ++l){
      const int use_ln = (l > 0);
      const int par = l & 1, opp = par ^ 1;
      const float* lg = l3g + (use_ln ? (l-1)*EE : 0);
      const float* lb = l3b + (use_ln ? (l-1)*EE : 0);
      float* kcl = kcache + (size_t)l*BB*EE*TT;
      float* vcl = vcache + (size_t)l*BB*EE*TT;
      k_A<<<16, 512, 0, stream>>>(x, yb[opp], lg, lb, use_ln,
          wqkvb + (size_t)l*3*EE*EE, saqb + (size_t)l*3*EE,
          owb + (size_t)l*EE*EE, kcl, vcl, xln, o2p[par], gs, tpos, tlen);
      k_BC<<<32, 512, 0, stream>>>(o2p[par], use_ln ? xln : x,
          saob + (size_t)l*EE, cac + (size_t)l*BB*EE,
          l1g + l*EE, l1b + l*EE, l2g + l*EE, l2b + l*EE, b2 + l*EE,
          w1b + (size_t)l*FFD*EE, b1 + l*FFD, w2b + (size_t)l*EE*FFD,
          yb[par], yb[opp], o2p[opp], (l == 1) ? x : nullptr);
    }
    k_logits_e<<<256, 256, 0, stream>>>(yb[1], l3g + 3*EE, l3b + 3*EE, outwb, outb,
        gumb + (size_t)step*BB*VV, el, eg, gs);
    k_SMEM<<<256, 256, 0, stream>>>(eTb, el, eg, gs, dseq,
        ddistbase + (size_t)step*BB*VV, x, step);
  }
}